// Round 2
// baseline (1274.938 us; speedup 1.0000x reference)
//
#include <hip/hip_runtime.h>

// ===========================================================================
// Compile-time sparsity pattern for the real-basis Wigner-3j contraction.
//
// Real-basis selection rules (exact superset of the nonzeros):
//   |m3| in { |m1|+|m2| , ||m1|-|m2|| }
//   #negative-m indices among (m1,m2,m3) must be even
// => for each (m1,m2,|m3|) the sign of m3 is forced.
// ===========================================================================

struct Entry {
  signed char l1, l2, l3;   // triple (weight lookup)
  signed char m1, m2, m3;   // real-basis m indices (weight lookup)
  signed char xi, yi, si;   // flat indices into x[16], y[16], acc[25]
};

constexpr int MAXE = 2048;

struct Pattern {
  Entry e[MAXE];
  int n;
};

constexpr Pattern build_pattern() {
  Pattern p{};
  p.n = 0;
  for (int l1 = 0; l1 <= 3; ++l1)
    for (int l2 = 0; l2 <= 3; ++l2)
      for (int m1 = -l1; m1 <= l1; ++m1)
        for (int m2 = -l2; m2 <= l2; ++m2) {
          int a1 = m1 < 0 ? -m1 : m1;
          int a2 = m2 < 0 ? -m2 : m2;
          int Ms = a1 + a2;
          int Md = a1 > a2 ? a1 - a2 : a2 - a1;
          int odd = ((m1 < 0 ? 1 : 0) + (m2 < 0 ? 1 : 0)) & 1;
          int lo = l1 > l2 ? l1 - l2 : l2 - l1;
          int hi = (l1 + l2 < 4) ? (l1 + l2) : 4;
          for (int l3 = lo; l3 <= hi; ++l3) {
            if ((l1 + l2 + l3) & 1) continue;   // parity rule of TRIPLES
            for (int c = 0; c < 2; ++c) {
              if (c == 1 && Md == Ms) continue; // dedupe when min(|m1|,|m2|)==0
              int M = (c == 0) ? Ms : Md;
              if (M > l3) continue;
              int m3 = 0;
              if (odd) {
                if (M == 0) continue;           // sin-parity forbids m3==0
                m3 = -M;
              } else {
                m3 = M;
              }
              p.e[p.n].l1 = (signed char)l1;
              p.e[p.n].l2 = (signed char)l2;
              p.e[p.n].l3 = (signed char)l3;
              p.e[p.n].m1 = (signed char)m1;
              p.e[p.n].m2 = (signed char)m2;
              p.e[p.n].m3 = (signed char)m3;
              p.e[p.n].xi = (signed char)(l1 * l1 + l1 + m1);
              p.e[p.n].yi = (signed char)(l2 * l2 + l2 + m2);
              p.e[p.n].si = (signed char)(l3 * l3 + l3 + m3);
              ++p.n;
            }
          }
        }
  return p;
}

constexpr Pattern PAT = build_pattern();
constexpr int NPAT = PAT.n;
static_assert(NPAT > 0 && NPAT < MAXE, "pattern size sanity");

// ===========================================================================
// Compile-time Wigner-3j (real basis) — constexpr port of the reference math.
// All weights become literal constants in the instruction stream: no runtime
// weight loads, no workspace, no H2D memcpy in the graph.
// ===========================================================================

constexpr double cfact(int n) {
  double r = 1.0;
  for (int i = 2; i <= n; ++i) r *= (double)i;
  return r;
}

constexpr double csqrt_(double x) {
  if (x <= 0.0) return 0.0;
  double g = x > 1.0 ? x : 1.0;
  for (int i = 0; i < 60; ++i) g = 0.5 * (g + x / g);
  return g;
}

struct cxd { double re, im; };

constexpr double cg_coeff(int j1, int m1, int j2, int m2, int j3, int m3) {
  if (m3 != m1 + m2) return 0.0;
  int vmin = -j1 + j2 + m3;
  if (-j1 + m1 > vmin) vmin = -j1 + m1;
  if (0 > vmin) vmin = 0;
  int vmax = j2 + j3 + m1;
  if (j3 - j1 + j2 < vmax) vmax = j3 - j1 + j2;
  if (j3 + m3 < vmax) vmax = j3 + m3;
  if (vmax < vmin) return 0.0;
  double C = csqrt_((2.0 * j3 + 1.0) * cfact(j3 + j1 - j2) * cfact(j3 - j1 + j2) *
                    cfact(j1 + j2 - j3) * cfact(j3 + m3) * cfact(j3 - m3) /
                    (cfact(j1 + j2 + j3 + 1) * cfact(j1 - m1) * cfact(j1 + m1) *
                     cfact(j2 - m2) * cfact(j2 + m2)));
  double S = 0.0;
  for (int v = vmin; v <= vmax; ++v) {
    double sgn = ((v + j2 + m2) & 1) ? -1.0 : 1.0;
    S += sgn * cfact(j2 + j3 + m1 - v) * cfact(j1 - m1 + v) /
         (cfact(v) * cfact(j3 - j1 + j2 - v) * cfact(j3 + m3 - v) *
          cfact(j1 - j2 - m3 + v));
  }
  return C * S;
}

constexpr void r2c(int l, cxd (&Q)[9][9]) {
  for (int i = 0; i < 9; ++i)
    for (int j = 0; j < 9; ++j) Q[i][j] = cxd{0.0, 0.0};
  const double s2 = 1.0 / csqrt_(2.0);
  for (int m = -l; m < 0; ++m) {
    Q[l + m][l - m] = cxd{s2, 0.0};     // column l + |m|
    Q[l + m][l + m] = cxd{0.0, -s2};    // column l - |m|
  }
  Q[l][l] = cxd{1.0, 0.0};
  for (int m = 1; m <= l; ++m) {
    double sgn = (m & 1) ? -1.0 : 1.0;
    Q[l + m][l + m] = cxd{sgn * s2, 0.0};
    Q[l + m][l - m] = cxd{0.0, sgn * s2};
  }
  cxd ph{1.0, 0.0};
  for (int i = 0; i < l; ++i) {         // ph *= -i
    cxd np{ph.im, -ph.re};
    ph = np;
  }
  for (int i = 0; i < 2 * l + 1; ++i)
    for (int j = 0; j < 2 * l + 1; ++j) {
      cxd q = Q[i][j];
      Q[i][j] = cxd{q.re * ph.re - q.im * ph.im, q.re * ph.im + q.im * ph.re};
    }
}

// W is [7][7][9]; only [n1][n2][n3] is meaningful.
constexpr void wigner3j_ce(int l1, int l2, int l3, double (&W)[7][7][9]) {
  const int n1 = 2 * l1 + 1, n2 = 2 * l2 + 1, n3 = 2 * l3 + 1;
  for (int j = 0; j < 7; ++j)
    for (int lc = 0; lc < 7; ++lc)
      for (int n = 0; n < 9; ++n) W[j][lc][n] = 0.0;
  cxd Q1[9][9] = {}, Q2[9][9] = {}, Q3[9][9] = {};
  r2c(l1, Q1);
  r2c(l2, Q2);
  r2c(l3, Q3);
  // einsum('ij,kl,mn,ikm->jln', Q1,Q2,Q3,CG), real part.
  for (int i = 0; i < n1; ++i) {
    const int m1 = i - l1;
    for (int k = 0; k < n2; ++k) {
      const int m2 = k - l2;
      const int m3 = m1 + m2;
      if (m3 < -l3 || m3 > l3) continue;
      const double c = cg_coeff(l1, m1, l2, m2, l3, m3);
      if (c == 0.0) continue;
      const int mr = l3 + m3;
      for (int j = 0; j < n1; ++j) {
        const cxd q1 = Q1[i][j];
        if (q1.re == 0.0 && q1.im == 0.0) continue;
        for (int lc = 0; lc < n2; ++lc) {
          const cxd q2 = Q2[k][lc];
          if (q2.re == 0.0 && q2.im == 0.0) continue;
          const cxd q12{q1.re * q2.re - q1.im * q2.im,
                        q1.re * q2.im + q1.im * q2.re};
          for (int n = 0; n < n3; ++n) {
            const cxd q3 = Q3[mr][n];
            if (q3.re == 0.0 && q3.im == 0.0) continue;
            W[j][lc][n] += (q12.re * q3.re - q12.im * q3.im) * c;
          }
        }
      }
    }
  }
  double nrm = 0.0;
  for (int j = 0; j < n1; ++j)
    for (int lc = 0; lc < n2; ++lc)
      for (int n = 0; n < n3; ++n) nrm += W[j][lc][n] * W[j][lc][n];
  nrm = csqrt_(nrm);
  if (nrm > 0.0)
    for (int j = 0; j < n1; ++j)
      for (int lc = 0; lc < n2; ++lc)
        for (int n = 0; n < n3; ++n) W[j][lc][n] /= nrm;
}

struct WTab { float w[MAXE]; };

constexpr WTab build_wtab() {
  WTab t{};
  for (int l1 = 0; l1 <= 3; ++l1)
    for (int l2 = 0; l2 <= 3; ++l2) {
      int lo = l1 > l2 ? l1 - l2 : l2 - l1;
      int hi = (l1 + l2 < 4) ? (l1 + l2) : 4;
      for (int l3 = lo; l3 <= hi; ++l3) {
        if ((l1 + l2 + l3) & 1) continue;
        double W[7][7][9] = {};
        wigner3j_ce(l1, l2, l3, W);
        for (int k = 0; k < NPAT; ++k) {
          const Entry& e = PAT.e[k];
          if (e.l1 == l1 && e.l2 == l2 && e.l3 == l3)
            t.w[k] = (float)W[l1 + e.m1][l2 + e.m2][l3 + e.m3];
        }
      }
    }
  return t;
}

constexpr WTab WTS = build_wtab();

// ---------------------------------------------------------------------------
// Compact (drop exact zeros) AND group by output index si, so the kernel can
// use one scalar accumulator per output and retire it to LDS immediately.
// This cuts peak live registers from {x16,y16,acc25}=57 to {x16,y16,acc1}=33.
// ---------------------------------------------------------------------------

struct GPat {
  int beg[26];                       // group s occupies [beg[s], beg[s+1])
  signed char xi[MAXE], yi[MAXE];
  float w[MAXE];
};

constexpr GPat build_gpat() {
  GPat g{};
  int n = 0;
  for (int s = 0; s < 25; ++s) {
    g.beg[s] = n;
    for (int k = 0; k < NPAT; ++k) {
      if (PAT.e[k].si != s) continue;
      if (WTS.w[k] == 0.0f) continue;
      g.xi[n] = PAT.e[k].xi;
      g.yi[n] = PAT.e[k].yi;
      g.w[n] = WTS.w[k];
      ++n;
    }
  }
  g.beg[25] = n;
  return g;
}

constexpr GPat GP = build_gpat();
constexpr int NNZ = GP.beg[25];
static_assert(NNZ > 0 && NNZ <= NPAT, "nnz sanity");

// ===========================================================================
// Kernel: one thread per (node, channel) pair.
//   x[16], y[16] via aligned float4 loads (pair stride = 64 B).
//   Fully-unrolled FMA chains with LITERAL weight constants; entries grouped
//   by output index so each scalar accumulator retires to LDS as soon as its
//   group completes -> low VGPR -> 6 waves/SIMD (matches the LDS cap of
//   6 blocks/CU). LDS dword index 25*t+s aliases only 2-way (free).
//   Output staged through LDS -> fully coalesced float4 stores.
// ===========================================================================

__global__ __launch_bounds__(256, 6) void cp3j_kernel(const float* __restrict__ t1,
                                                      const float* __restrict__ t2,
                                                      float* __restrict__ out) {
  __shared__ float4 lds4[1600];                    // 256 pairs * 25 floats
  float* lds = reinterpret_cast<float*>(lds4);
  const int t = threadIdx.x;
  const int pair = blockIdx.x * 256 + t;

  const float4* a4 = reinterpret_cast<const float4*>(t1) + (size_t)pair * 4;
  const float4* b4 = reinterpret_cast<const float4*>(t2) + (size_t)pair * 4;
  float x[16], y[16];
#pragma unroll
  for (int i = 0; i < 4; ++i) {
    float4 va = a4[i];
    float4 vb = b4[i];
    x[4 * i + 0] = va.x; x[4 * i + 1] = va.y; x[4 * i + 2] = va.z; x[4 * i + 3] = va.w;
    y[4 * i + 0] = vb.x; y[4 * i + 1] = vb.y; y[4 * i + 2] = vb.z; y[4 * i + 3] = vb.w;
  }

#pragma unroll
  for (int s = 0; s < 25; ++s) {
    float a = 0.0f;
#pragma unroll
    for (int k = GP.beg[s]; k < GP.beg[s + 1]; ++k) {
      a = fmaf(GP.w[k], x[GP.xi[k]] * y[GP.yi[k]], a);
    }
    lds[t * 25 + s] = a;                 // retire accumulator immediately
  }
  __syncthreads();

  float4* o4 = reinterpret_cast<float4*>(out + (size_t)blockIdx.x * 6400);
#pragma unroll
  for (int i = 0; i < 6; ++i) o4[t + i * 256] = lds4[t + i * 256];
  if (t < 64) o4[1536 + t] = lds4[1536 + t];
}

// ===========================================================================

extern "C" void kernel_launch(void* const* d_in, const int* in_sizes, int n_in,
                              void* d_out, int out_size, void* d_ws, size_t ws_size,
                              hipStream_t stream) {
  const float* t1 = (const float*)d_in[0];
  const float* t2 = (const float*)d_in[1];
  float* out = (float*)d_out;
  (void)d_ws; (void)ws_size; (void)n_in; (void)out_size;

  const int pairs = in_sizes[0] / 16;      // 50000 * 64 = 3,200,000
  const int blocks = pairs / 256;          // exactly 12500, no tail
  cp3j_kernel<<<blocks, 256, 0, stream>>>(t1, t2, out);
}

// Round 5
// 568.304 us; speedup vs baseline: 2.2434x; 2.2434x over previous
//
#include <hip/hip_runtime.h>

// ===========================================================================
// Compile-time sparsity pattern for the real-basis Wigner-3j contraction.
//
// Real-basis selection rules (exact superset of the nonzeros):
//   |m3| in { |m1|+|m2| , ||m1|-|m2|| }
//   #negative-m indices among (m1,m2,m3) must be even
// => for each (m1,m2,|m3|) the sign of m3 is forced.
// ===========================================================================

struct Entry {
  signed char l1, l2, l3;   // triple (weight lookup)
  signed char m1, m2, m3;   // real-basis m indices (weight lookup)
  signed char xi, yi, si;   // flat indices into x[16], y[16], acc[25]
};

constexpr int MAXE = 2048;

struct Pattern {
  Entry e[MAXE];
  int n;
};

constexpr Pattern build_pattern() {
  Pattern p{};
  p.n = 0;
  for (int l1 = 0; l1 <= 3; ++l1)
    for (int l2 = 0; l2 <= 3; ++l2)
      for (int m1 = -l1; m1 <= l1; ++m1)
        for (int m2 = -l2; m2 <= l2; ++m2) {
          int a1 = m1 < 0 ? -m1 : m1;
          int a2 = m2 < 0 ? -m2 : m2;
          int Ms = a1 + a2;
          int Md = a1 > a2 ? a1 - a2 : a2 - a1;
          int odd = ((m1 < 0 ? 1 : 0) + (m2 < 0 ? 1 : 0)) & 1;
          int lo = l1 > l2 ? l1 - l2 : l2 - l1;
          int hi = (l1 + l2 < 4) ? (l1 + l2) : 4;
          for (int l3 = lo; l3 <= hi; ++l3) {
            if ((l1 + l2 + l3) & 1) continue;   // parity rule of TRIPLES
            for (int c = 0; c < 2; ++c) {
              if (c == 1 && Md == Ms) continue; // dedupe when min(|m1|,|m2|)==0
              int M = (c == 0) ? Ms : Md;
              if (M > l3) continue;
              int m3 = 0;
              if (odd) {
                if (M == 0) continue;           // sin-parity forbids m3==0
                m3 = -M;
              } else {
                m3 = M;
              }
              p.e[p.n].l1 = (signed char)l1;
              p.e[p.n].l2 = (signed char)l2;
              p.e[p.n].l3 = (signed char)l3;
              p.e[p.n].m1 = (signed char)m1;
              p.e[p.n].m2 = (signed char)m2;
              p.e[p.n].m3 = (signed char)m3;
              p.e[p.n].xi = (signed char)(l1 * l1 + l1 + m1);
              p.e[p.n].yi = (signed char)(l2 * l2 + l2 + m2);
              p.e[p.n].si = (signed char)(l3 * l3 + l3 + m3);
              ++p.n;
            }
          }
        }
  return p;
}

constexpr Pattern PAT = build_pattern();
constexpr int NPAT = PAT.n;
static_assert(NPAT > 0 && NPAT < MAXE, "pattern size sanity");

// ===========================================================================
// Compile-time Wigner-3j (real basis) — constexpr port of the reference math.
// All weights become literal constants in the instruction stream: no runtime
// weight loads, no workspace, no H2D memcpy in the graph.
// ===========================================================================

constexpr double cfact(int n) {
  double r = 1.0;
  for (int i = 2; i <= n; ++i) r *= (double)i;
  return r;
}

constexpr double csqrt_(double x) {
  if (x <= 0.0) return 0.0;
  double g = x > 1.0 ? x : 1.0;
  for (int i = 0; i < 60; ++i) g = 0.5 * (g + x / g);
  return g;
}

struct cxd { double re, im; };

constexpr double cg_coeff(int j1, int m1, int j2, int m2, int j3, int m3) {
  if (m3 != m1 + m2) return 0.0;
  int vmin = -j1 + j2 + m3;
  if (-j1 + m1 > vmin) vmin = -j1 + m1;
  if (0 > vmin) vmin = 0;
  int vmax = j2 + j3 + m1;
  if (j3 - j1 + j2 < vmax) vmax = j3 - j1 + j2;
  if (j3 + m3 < vmax) vmax = j3 + m3;
  if (vmax < vmin) return 0.0;
  double C = csqrt_((2.0 * j3 + 1.0) * cfact(j3 + j1 - j2) * cfact(j3 - j1 + j2) *
                    cfact(j1 + j2 - j3) * cfact(j3 + m3) * cfact(j3 - m3) /
                    (cfact(j1 + j2 + j3 + 1) * cfact(j1 - m1) * cfact(j1 + m1) *
                     cfact(j2 - m2) * cfact(j2 + m2)));
  double S = 0.0;
  for (int v = vmin; v <= vmax; ++v) {
    double sgn = ((v + j2 + m2) & 1) ? -1.0 : 1.0;
    S += sgn * cfact(j2 + j3 + m1 - v) * cfact(j1 - m1 + v) /
         (cfact(v) * cfact(j3 - j1 + j2 - v) * cfact(j3 + m3 - v) *
          cfact(j1 - j2 - m3 + v));
  }
  return C * S;
}

constexpr void r2c(int l, cxd (&Q)[9][9]) {
  for (int i = 0; i < 9; ++i)
    for (int j = 0; j < 9; ++j) Q[i][j] = cxd{0.0, 0.0};
  const double s2 = 1.0 / csqrt_(2.0);
  for (int m = -l; m < 0; ++m) {
    Q[l + m][l - m] = cxd{s2, 0.0};     // column l + |m|
    Q[l + m][l + m] = cxd{0.0, -s2};    // column l - |m|
  }
  Q[l][l] = cxd{1.0, 0.0};
  for (int m = 1; m <= l; ++m) {
    double sgn = (m & 1) ? -1.0 : 1.0;
    Q[l + m][l + m] = cxd{sgn * s2, 0.0};
    Q[l + m][l - m] = cxd{0.0, sgn * s2};
  }
  cxd ph{1.0, 0.0};
  for (int i = 0; i < l; ++i) {         // ph *= -i
    cxd np{ph.im, -ph.re};
    ph = np;
  }
  for (int i = 0; i < 2 * l + 1; ++i)
    for (int j = 0; j < 2 * l + 1; ++j) {
      cxd q = Q[i][j];
      Q[i][j] = cxd{q.re * ph.re - q.im * ph.im, q.re * ph.im + q.im * ph.re};
    }
}

// W is [7][7][9]; only [n1][n2][n3] is meaningful.
constexpr void wigner3j_ce(int l1, int l2, int l3, double (&W)[7][7][9]) {
  const int n1 = 2 * l1 + 1, n2 = 2 * l2 + 1, n3 = 2 * l3 + 1;
  for (int j = 0; j < 7; ++j)
    for (int lc = 0; lc < 7; ++lc)
      for (int n = 0; n < 9; ++n) W[j][lc][n] = 0.0;
  cxd Q1[9][9] = {}, Q2[9][9] = {}, Q3[9][9] = {};
  r2c(l1, Q1);
  r2c(l2, Q2);
  r2c(l3, Q3);
  // einsum('ij,kl,mn,ikm->jln', Q1,Q2,Q3,CG), real part.
  for (int i = 0; i < n1; ++i) {
    const int m1 = i - l1;
    for (int k = 0; k < n2; ++k) {
      const int m2 = k - l2;
      const int m3 = m1 + m2;
      if (m3 < -l3 || m3 > l3) continue;
      const double c = cg_coeff(l1, m1, l2, m2, l3, m3);
      if (c == 0.0) continue;
      const int mr = l3 + m3;
      for (int j = 0; j < n1; ++j) {
        const cxd q1 = Q1[i][j];
        if (q1.re == 0.0 && q1.im == 0.0) continue;
        for (int lc = 0; lc < n2; ++lc) {
          const cxd q2 = Q2[k][lc];
          if (q2.re == 0.0 && q2.im == 0.0) continue;
          const cxd q12{q1.re * q2.re - q1.im * q2.im,
                        q1.re * q2.im + q1.im * q2.re};
          for (int n = 0; n < n3; ++n) {
            const cxd q3 = Q3[mr][n];
            if (q3.re == 0.0 && q3.im == 0.0) continue;
            W[j][lc][n] += (q12.re * q3.re - q12.im * q3.im) * c;
          }
        }
      }
    }
  }
  double nrm = 0.0;
  for (int j = 0; j < n1; ++j)
    for (int lc = 0; lc < n2; ++lc)
      for (int n = 0; n < n3; ++n) nrm += W[j][lc][n] * W[j][lc][n];
  nrm = csqrt_(nrm);
  if (nrm > 0.0)
    for (int j = 0; j < n1; ++j)
      for (int lc = 0; lc < n2; ++lc)
        for (int n = 0; n < n3; ++n) W[j][lc][n] /= nrm;
}

struct WTab { float w[MAXE]; };

constexpr WTab build_wtab() {
  WTab t{};
  for (int l1 = 0; l1 <= 3; ++l1)
    for (int l2 = 0; l2 <= 3; ++l2) {
      int lo = l1 > l2 ? l1 - l2 : l2 - l1;
      int hi = (l1 + l2 < 4) ? (l1 + l2) : 4;
      for (int l3 = lo; l3 <= hi; ++l3) {
        if ((l1 + l2 + l3) & 1) continue;
        double W[7][7][9] = {};
        wigner3j_ce(l1, l2, l3, W);
        for (int k = 0; k < NPAT; ++k) {
          const Entry& e = PAT.e[k];
          if (e.l1 == l1 && e.l2 == l2 && e.l3 == l3)
            t.w[k] = (float)W[l1 + e.m1][l2 + e.m2][l3 + e.m3];
        }
      }
    }
  return t;
}

constexpr WTab WTS = build_wtab();

// Compact: drop entries whose weight is exactly zero (pattern is a superset).
struct FPat {
  signed char xi[MAXE], yi[MAXE], si[MAXE];
  float w[MAXE];
  int n;
};

constexpr FPat build_fpat() {
  FPat f{};
  f.n = 0;
  for (int k = 0; k < NPAT; ++k) {
    if (WTS.w[k] != 0.0f) {
      f.xi[f.n] = PAT.e[k].xi;
      f.yi[f.n] = PAT.e[k].yi;
      f.si[f.n] = PAT.e[k].si;
      f.w[f.n] = WTS.w[k];
      ++f.n;
    }
  }
  return f;
}

constexpr FPat FP = build_fpat();
constexpr int NNZ = FP.n;
static_assert(NNZ > 0 && NNZ <= NPAT, "nnz sanity");

// Native clang vector type: __builtin_nontemporal_store rejects HIP's
// float4 (a HIP_vector_type class), but accepts ext_vector_type.
typedef float f32x4 __attribute__((ext_vector_type(4)));

// ===========================================================================
// Kernel: one thread per (node, channel) pair.
//   x[16], y[16] via aligned float4 loads (pair stride = 64 B).
//   Fully-unrolled FMA chain with LITERAL weight constants (round-1 proven
//   structure, VGPR=88, no scratch). 25 independent accumulator chains.
//   NO __launch_bounds__ min-waves hint: round-2 showed pinning occupancy
//   below the dataflow's register floor makes the allocator spill ~600 B/thread
//   to scratch (hbm_bytes 0.53 -> 3.7 GB, dur 351 -> 908 us).
//   Output staged through PER-WAVE LDS regions (layout t*25+s is wave-local)
//   -> no __syncthreads needed; each wave's coalesced nontemporal f32x4
//   stores overlap other waves' FMA chains.
// ===========================================================================

__global__ __launch_bounds__(256) void cp3j_kernel(const float* __restrict__ t1,
                                                   const float* __restrict__ t2,
                                                   float* __restrict__ out) {
  __shared__ f32x4 lds4[1600];                     // 256 pairs * 25 floats
  float* lds = reinterpret_cast<float*>(lds4);
  const int t = threadIdx.x;
  const int wave = t >> 6;
  const int lane = t & 63;
  const int pair = blockIdx.x * 256 + t;

  const f32x4* a4 = reinterpret_cast<const f32x4*>(t1) + (size_t)pair * 4;
  const f32x4* b4 = reinterpret_cast<const f32x4*>(t2) + (size_t)pair * 4;
  float x[16], y[16];
#pragma unroll
  for (int i = 0; i < 4; ++i) {
    f32x4 va = a4[i];
    f32x4 vb = b4[i];
    x[4 * i + 0] = va.x; x[4 * i + 1] = va.y; x[4 * i + 2] = va.z; x[4 * i + 3] = va.w;
    y[4 * i + 0] = vb.x; y[4 * i + 1] = vb.y; y[4 * i + 2] = vb.z; y[4 * i + 3] = vb.w;
  }

  float acc[25];
#pragma unroll
  for (int s = 0; s < 25; ++s) acc[s] = 0.0f;

#pragma unroll
  for (int k = 0; k < NNZ; ++k) {
    acc[FP.si[k]] = fmaf(FP.w[k], x[FP.xi[k]] * y[FP.yi[k]], acc[FP.si[k]]);
  }

  // Stage this wave's 64 pairs (6400 B) in its own LDS region; write pattern
  // lane*25+s is a permutation mod 32 banks (25 odd) -> only the free 2-way
  // wave64 aliasing. Wave-internal exchange: lockstep + compiler-inserted
  // lgkmcnt waits make this safe without a block barrier.
#pragma unroll
  for (int s = 0; s < 25; ++s) lds[wave * 1600 + lane * 25 + s] = acc[s];

  // Coalesced copy of this wave's region: 400 f32x4 per wave.
  const f32x4* wlds4 = lds4 + wave * 400;
  f32x4* o4 = reinterpret_cast<f32x4*>(out + (size_t)blockIdx.x * 6400 + wave * 1600);
#pragma unroll
  for (int i = 0; i < 6; ++i)
    __builtin_nontemporal_store(wlds4[lane + i * 64], &o4[lane + i * 64]);
  if (lane < 16)
    __builtin_nontemporal_store(wlds4[384 + lane], &o4[384 + lane]);
}

// ===========================================================================

extern "C" void kernel_launch(void* const* d_in, const int* in_sizes, int n_in,
                              void* d_out, int out_size, void* d_ws, size_t ws_size,
                              hipStream_t stream) {
  const float* t1 = (const float*)d_in[0];
  const float* t2 = (const float*)d_in[1];
  float* out = (float*)d_out;
  (void)d_ws; (void)ws_size; (void)n_in; (void)out_size;

  const int pairs = in_sizes[0] / 16;      // 50000 * 64 = 3,200,000
  const int blocks = pairs / 256;          // exactly 12500, no tail
  cp3j_kernel<<<blocks, 256, 0, stream>>>(t1, t2, out);
}

// Round 6
// 546.560 us; speedup vs baseline: 2.3327x; 1.0398x over previous
//
#include <hip/hip_runtime.h>

// ===========================================================================
// Compile-time sparsity pattern for the real-basis Wigner-3j contraction.
//
// Real-basis selection rules (exact superset of the nonzeros):
//   |m3| in { |m1|+|m2| , ||m1|-|m2|| }
//   #negative-m indices among (m1,m2,m3) must be even
// => for each (m1,m2,|m3|) the sign of m3 is forced.
// ===========================================================================

struct Entry {
  signed char l1, l2, l3;   // triple (weight lookup)
  signed char m1, m2, m3;   // real-basis m indices (weight lookup)
  signed char xi, yi, si;   // flat indices into x[16], y[16], acc[25]
};

constexpr int MAXE = 2048;

struct Pattern {
  Entry e[MAXE];
  int n;
};

constexpr Pattern build_pattern() {
  Pattern p{};
  p.n = 0;
  for (int l1 = 0; l1 <= 3; ++l1)
    for (int l2 = 0; l2 <= 3; ++l2)
      for (int m1 = -l1; m1 <= l1; ++m1)
        for (int m2 = -l2; m2 <= l2; ++m2) {
          int a1 = m1 < 0 ? -m1 : m1;
          int a2 = m2 < 0 ? -m2 : m2;
          int Ms = a1 + a2;
          int Md = a1 > a2 ? a1 - a2 : a2 - a1;
          int odd = ((m1 < 0 ? 1 : 0) + (m2 < 0 ? 1 : 0)) & 1;
          int lo = l1 > l2 ? l1 - l2 : l2 - l1;
          int hi = (l1 + l2 < 4) ? (l1 + l2) : 4;
          for (int l3 = lo; l3 <= hi; ++l3) {
            if ((l1 + l2 + l3) & 1) continue;   // parity rule of TRIPLES
            for (int c = 0; c < 2; ++c) {
              if (c == 1 && Md == Ms) continue; // dedupe when min(|m1|,|m2|)==0
              int M = (c == 0) ? Ms : Md;
              if (M > l3) continue;
              int m3 = 0;
              if (odd) {
                if (M == 0) continue;           // sin-parity forbids m3==0
                m3 = -M;
              } else {
                m3 = M;
              }
              p.e[p.n].l1 = (signed char)l1;
              p.e[p.n].l2 = (signed char)l2;
              p.e[p.n].l3 = (signed char)l3;
              p.e[p.n].m1 = (signed char)m1;
              p.e[p.n].m2 = (signed char)m2;
              p.e[p.n].m3 = (signed char)m3;
              p.e[p.n].xi = (signed char)(l1 * l1 + l1 + m1);
              p.e[p.n].yi = (signed char)(l2 * l2 + l2 + m2);
              p.e[p.n].si = (signed char)(l3 * l3 + l3 + m3);
              ++p.n;
            }
          }
        }
  return p;
}

constexpr Pattern PAT = build_pattern();
constexpr int NPAT = PAT.n;
static_assert(NPAT > 0 && NPAT < MAXE, "pattern size sanity");

// ===========================================================================
// Compile-time Wigner-3j (real basis) — constexpr port of the reference math.
// All weights become literal constants in the instruction stream: no runtime
// weight loads, no workspace, no H2D memcpy in the graph.
// ===========================================================================

constexpr double cfact(int n) {
  double r = 1.0;
  for (int i = 2; i <= n; ++i) r *= (double)i;
  return r;
}

constexpr double csqrt_(double x) {
  if (x <= 0.0) return 0.0;
  double g = x > 1.0 ? x : 1.0;
  for (int i = 0; i < 60; ++i) g = 0.5 * (g + x / g);
  return g;
}

struct cxd { double re, im; };

constexpr double cg_coeff(int j1, int m1, int j2, int m2, int j3, int m3) {
  if (m3 != m1 + m2) return 0.0;
  int vmin = -j1 + j2 + m3;
  if (-j1 + m1 > vmin) vmin = -j1 + m1;
  if (0 > vmin) vmin = 0;
  int vmax = j2 + j3 + m1;
  if (j3 - j1 + j2 < vmax) vmax = j3 - j1 + j2;
  if (j3 + m3 < vmax) vmax = j3 + m3;
  if (vmax < vmin) return 0.0;
  double C = csqrt_((2.0 * j3 + 1.0) * cfact(j3 + j1 - j2) * cfact(j3 - j1 + j2) *
                    cfact(j1 + j2 - j3) * cfact(j3 + m3) * cfact(j3 - m3) /
                    (cfact(j1 + j2 + j3 + 1) * cfact(j1 - m1) * cfact(j1 + m1) *
                     cfact(j2 - m2) * cfact(j2 + m2)));
  double S = 0.0;
  for (int v = vmin; v <= vmax; ++v) {
    double sgn = ((v + j2 + m2) & 1) ? -1.0 : 1.0;
    S += sgn * cfact(j2 + j3 + m1 - v) * cfact(j1 - m1 + v) /
         (cfact(v) * cfact(j3 - j1 + j2 - v) * cfact(j3 + m3 - v) *
          cfact(j1 - j2 - m3 + v));
  }
  return C * S;
}

constexpr void r2c(int l, cxd (&Q)[9][9]) {
  for (int i = 0; i < 9; ++i)
    for (int j = 0; j < 9; ++j) Q[i][j] = cxd{0.0, 0.0};
  const double s2 = 1.0 / csqrt_(2.0);
  for (int m = -l; m < 0; ++m) {
    Q[l + m][l - m] = cxd{s2, 0.0};     // column l + |m|
    Q[l + m][l + m] = cxd{0.0, -s2};    // column l - |m|
  }
  Q[l][l] = cxd{1.0, 0.0};
  for (int m = 1; m <= l; ++m) {
    double sgn = (m & 1) ? -1.0 : 1.0;
    Q[l + m][l + m] = cxd{sgn * s2, 0.0};
    Q[l + m][l - m] = cxd{0.0, sgn * s2};
  }
  cxd ph{1.0, 0.0};
  for (int i = 0; i < l; ++i) {         // ph *= -i
    cxd np{ph.im, -ph.re};
    ph = np;
  }
  for (int i = 0; i < 2 * l + 1; ++i)
    for (int j = 0; j < 2 * l + 1; ++j) {
      cxd q = Q[i][j];
      Q[i][j] = cxd{q.re * ph.re - q.im * ph.im, q.re * ph.im + q.im * ph.re};
    }
}

// W is [7][7][9]; only [n1][n2][n3] is meaningful.
constexpr void wigner3j_ce(int l1, int l2, int l3, double (&W)[7][7][9]) {
  const int n1 = 2 * l1 + 1, n2 = 2 * l2 + 1, n3 = 2 * l3 + 1;
  for (int j = 0; j < 7; ++j)
    for (int lc = 0; lc < 7; ++lc)
      for (int n = 0; n < 9; ++n) W[j][lc][n] = 0.0;
  cxd Q1[9][9] = {}, Q2[9][9] = {}, Q3[9][9] = {};
  r2c(l1, Q1);
  r2c(l2, Q2);
  r2c(l3, Q3);
  // einsum('ij,kl,mn,ikm->jln', Q1,Q2,Q3,CG), real part.
  for (int i = 0; i < n1; ++i) {
    const int m1 = i - l1;
    for (int k = 0; k < n2; ++k) {
      const int m2 = k - l2;
      const int m3 = m1 + m2;
      if (m3 < -l3 || m3 > l3) continue;
      const double c = cg_coeff(l1, m1, l2, m2, l3, m3);
      if (c == 0.0) continue;
      const int mr = l3 + m3;
      for (int j = 0; j < n1; ++j) {
        const cxd q1 = Q1[i][j];
        if (q1.re == 0.0 && q1.im == 0.0) continue;
        for (int lc = 0; lc < n2; ++lc) {
          const cxd q2 = Q2[k][lc];
          if (q2.re == 0.0 && q2.im == 0.0) continue;
          const cxd q12{q1.re * q2.re - q1.im * q2.im,
                        q1.re * q2.im + q1.im * q2.re};
          for (int n = 0; n < n3; ++n) {
            const cxd q3 = Q3[mr][n];
            if (q3.re == 0.0 && q3.im == 0.0) continue;
            W[j][lc][n] += (q12.re * q3.re - q12.im * q3.im) * c;
          }
        }
      }
    }
  }
  double nrm = 0.0;
  for (int j = 0; j < n1; ++j)
    for (int lc = 0; lc < n2; ++lc)
      for (int n = 0; n < n3; ++n) nrm += W[j][lc][n] * W[j][lc][n];
  nrm = csqrt_(nrm);
  if (nrm > 0.0)
    for (int j = 0; j < n1; ++j)
      for (int lc = 0; lc < n2; ++lc)
        for (int n = 0; n < n3; ++n) W[j][lc][n] /= nrm;
}

struct WTab { float w[MAXE]; };

constexpr WTab build_wtab() {
  WTab t{};
  for (int l1 = 0; l1 <= 3; ++l1)
    for (int l2 = 0; l2 <= 3; ++l2) {
      int lo = l1 > l2 ? l1 - l2 : l2 - l1;
      int hi = (l1 + l2 < 4) ? (l1 + l2) : 4;
      for (int l3 = lo; l3 <= hi; ++l3) {
        if ((l1 + l2 + l3) & 1) continue;
        double W[7][7][9] = {};
        wigner3j_ce(l1, l2, l3, W);
        for (int k = 0; k < NPAT; ++k) {
          const Entry& e = PAT.e[k];
          if (e.l1 == l1 && e.l2 == l2 && e.l3 == l3)
            t.w[k] = (float)W[l1 + e.m1][l2 + e.m2][l3 + e.m3];
        }
      }
    }
  return t;
}

constexpr WTab WTS = build_wtab();

// ---------------------------------------------------------------------------
// Compact (drop exact zeros) AND group by output index si: one scalar
// accumulator at a time, retired to LDS as soon as its group completes.
// Per-si accumulation order is k-ascending — numerically identical to the
// flat acc[25] chain already verified (absmax 0.03125).
// Mandatory live state drops {x16,y16,acc25}=57 -> {x16,y16,acc1}=33,
// targeting natural VGPR <= 64 (the occupancy-quantum cliff: 65..128 VGPR
// all cost the same 4 waves/SIMD; <=64 gives 8).
// NO __launch_bounds__ min-waves hint — round-2 proved forcing a register
// budget below the dataflow's floor spills to scratch (3.7 GB HBM, 908 us).
// ---------------------------------------------------------------------------

struct GPat {
  int beg[26];                       // group s occupies [beg[s], beg[s+1])
  signed char xi[MAXE], yi[MAXE];
  float w[MAXE];
};

constexpr GPat build_gpat() {
  GPat g{};
  int n = 0;
  for (int s = 0; s < 25; ++s) {
    g.beg[s] = n;
    for (int k = 0; k < NPAT; ++k) {
      if (PAT.e[k].si != s) continue;
      if (WTS.w[k] == 0.0f) continue;
      g.xi[n] = PAT.e[k].xi;
      g.yi[n] = PAT.e[k].yi;
      g.w[n] = WTS.w[k];
      ++n;
    }
  }
  g.beg[25] = n;
  return g;
}

constexpr GPat GP = build_gpat();
constexpr int NNZ = GP.beg[25];
static_assert(NNZ > 0 && NNZ <= NPAT, "nnz sanity");

// Native clang vector type: __builtin_nontemporal_store rejects HIP's
// float4 (a HIP_vector_type class), but accepts ext_vector_type.
typedef float f32x4 __attribute__((ext_vector_type(4)));

// ===========================================================================
// Kernel: one thread per (node, channel) pair.
//   x[16], y[16] via aligned f32x4 loads (pair stride = 64 B).
//   Fully-unrolled FMA chains with LITERAL weight constants, grouped by
//   output index si; each group's scalar accumulator is ds_written to the
//   wave's LDS staging region immediately (early retire -> low VGPR).
//   Per-wave LDS regions (lane*25+s is wave-local) -> no __syncthreads;
//   coalesced nontemporal f32x4 stores per wave.
// ===========================================================================

__global__ __launch_bounds__(256) void cp3j_kernel(const float* __restrict__ t1,
                                                   const float* __restrict__ t2,
                                                   float* __restrict__ out) {
  __shared__ f32x4 lds4[1600];                     // 256 pairs * 25 floats
  float* lds = reinterpret_cast<float*>(lds4);
  const int t = threadIdx.x;
  const int wave = t >> 6;
  const int lane = t & 63;
  const int pair = blockIdx.x * 256 + t;

  const f32x4* a4 = reinterpret_cast<const f32x4*>(t1) + (size_t)pair * 4;
  const f32x4* b4 = reinterpret_cast<const f32x4*>(t2) + (size_t)pair * 4;
  float x[16], y[16];
#pragma unroll
  for (int i = 0; i < 4; ++i) {
    f32x4 va = a4[i];
    f32x4 vb = b4[i];
    x[4 * i + 0] = va.x; x[4 * i + 1] = va.y; x[4 * i + 2] = va.z; x[4 * i + 3] = va.w;
    y[4 * i + 0] = vb.x; y[4 * i + 1] = vb.y; y[4 * i + 2] = vb.z; y[4 * i + 3] = vb.w;
  }

  // Per-group scalar accumulator, retired to LDS immediately. LDS write
  // pattern lane*25+s: 25 odd -> permutation mod 32 banks, only the free
  // 2-way wave64 aliasing. Wave-internal exchange -> no block barrier.
  float* wl = lds + wave * 1600 + lane * 25;
#pragma unroll
  for (int s = 0; s < 25; ++s) {
    float a = 0.0f;
#pragma unroll
    for (int k = GP.beg[s]; k < GP.beg[s + 1]; ++k) {
      a = fmaf(GP.w[k], x[GP.xi[k]] * y[GP.yi[k]], a);
    }
    wl[s] = a;
  }

  // Coalesced copy of this wave's region: 400 f32x4 per wave.
  const f32x4* wlds4 = lds4 + wave * 400;
  f32x4* o4 = reinterpret_cast<f32x4*>(out + (size_t)blockIdx.x * 6400 + wave * 1600);
#pragma unroll
  for (int i = 0; i < 6; ++i)
    __builtin_nontemporal_store(wlds4[lane + i * 64], &o4[lane + i * 64]);
  if (lane < 16)
    __builtin_nontemporal_store(wlds4[384 + lane], &o4[384 + lane]);
}

// ===========================================================================

extern "C" void kernel_launch(void* const* d_in, const int* in_sizes, int n_in,
                              void* d_out, int out_size, void* d_ws, size_t ws_size,
                              hipStream_t stream) {
  const float* t1 = (const float*)d_in[0];
  const float* t2 = (const float*)d_in[1];
  float* out = (float*)d_out;
  (void)d_ws; (void)ws_size; (void)n_in; (void)out_size;

  const int pairs = in_sizes[0] / 16;      // 50000 * 64 = 3,200,000
  const int blocks = pairs / 256;          // exactly 12500, no tail
  cp3j_kernel<<<blocks, 256, 0, stream>>>(t1, t2, out);
}